// Round 3
// baseline (16688.725 us; speedup 1.0000x reference)
//
#include <hip/hip_runtime.h>
#include <cstdint>

typedef float vf2 __attribute__((ext_vector_type(2)));

#define GB_M 128
#define GB_N 64
#define GB_K 16

// C[m,n] = act( sum_k A[row(m),k]*B[n,k] + bias[n] )
__global__ __launch_bounds__(256) void gemm_bt_f32(
    const float* __restrict__ A, const float* __restrict__ B,
    const float* __restrict__ bias, float* __restrict__ C,
    int Mc, int N, int K, int tc_shift, int Tfull, int t0, int act)
{
  __shared__ float As[GB_K][GB_M + 4];
  __shared__ float Bs[GB_K][GB_N + 4];
  const int tid = threadIdx.x;
  const int m0 = blockIdx.y * GB_M;
  const int n0 = blockIdx.x * GB_N;
  const int tx = tid & 15;
  const int ty = tid >> 4;

  const int tcmask = (1 << tc_shift) - 1;
  int arow[2];
#pragma unroll
  for (int i = 0; i < 2; i++) {
    int f = tid + i * 256;
    int row = f >> 2;
    int rc = m0 + row;
    arow[i] = (rc >> tc_shift) * Tfull + t0 + (rc & tcmask);
  }
  const int akq = tid & 3;
  const int brow = tid >> 2;
  const int bn = n0 + brow;

  vf2 acc2[4][4];
#pragma unroll
  for (int i = 0; i < 4; i++)
#pragma unroll
    for (int j = 0; j < 4; j++) acc2[i][j] = (vf2)(0.f);

  for (int k0 = 0; k0 < K; k0 += GB_K) {
#pragma unroll
    for (int i = 0; i < 2; i++) {
      int f = tid + i * 256;
      int row = f >> 2;
      float4 v = *(const float4*)(A + (size_t)arow[i] * K + k0 + akq * 4);
      As[akq * 4 + 0][row] = v.x; As[akq * 4 + 1][row] = v.y;
      As[akq * 4 + 2][row] = v.z; As[akq * 4 + 3][row] = v.w;
    }
    {
      float4 v = make_float4(0.f, 0.f, 0.f, 0.f);
      if (bn < N) v = *(const float4*)(B + (size_t)bn * K + k0 + akq * 4);
      Bs[akq * 4 + 0][brow] = v.x; Bs[akq * 4 + 1][brow] = v.y;
      Bs[akq * 4 + 2][brow] = v.z; Bs[akq * 4 + 3][brow] = v.w;
    }
    __syncthreads();
#pragma unroll
    for (int k = 0; k < GB_K; k++) {
      float4 a0 = *(const float4*)&As[k][ty * 8];
      float4 a1 = *(const float4*)&As[k][ty * 8 + 4];
      float4 b0 = *(const float4*)&Bs[k][tx * 4];
      vf2 a2[4];
      a2[0] = (vf2){a0.x, a0.y}; a2[1] = (vf2){a0.z, a0.w};
      a2[2] = (vf2){a1.x, a1.y}; a2[3] = (vf2){a1.z, a1.w};
      float bv[4] = {b0.x, b0.y, b0.z, b0.w};
#pragma unroll
      for (int j = 0; j < 4; j++) {
        vf2 bs = (vf2){bv[j], bv[j]};
#pragma unroll
        for (int ip = 0; ip < 4; ip++)
          acc2[ip][j] = __builtin_elementwise_fma(a2[ip], bs, acc2[ip][j]);
      }
    }
    __syncthreads();
  }

#pragma unroll
  for (int j = 0; j < 4; j++) {
    int n = n0 + tx * 4 + j;
    if (n >= N) continue;
    float bz = bias[n];
#pragma unroll
    for (int i = 0; i < 8; i++) {
      int m = m0 + ty * 8 + i;
      float x = ((i & 1) ? acc2[i >> 1][j].y : acc2[i >> 1][j].x) + bz;
      if (act == 1) {
        x = 1.0507009873554805f * (x > 0.f ? x : 1.6732632423543772f * (__expf(x) - 1.f));
      } else if (act == 2) {
        x = tanhf(x);
      }
      C[(size_t)m * N + n] = x;
    }
  }
}

#define RT 384
#define RNWG 256

__device__ __forceinline__ void pollge(const unsigned* fp, unsigned want) {
  while (__hip_atomic_load(fp, __ATOMIC_RELAXED, __HIP_MEMORY_SCOPE_AGENT) < want)
    __builtin_amdgcn_s_sleep(1);
}

// Persistent GRU recurrence, round-7: MERGED single communication round per
// timestep (was 2 staggered X/Y rounds at 5.5us/step, wait-bound: VALUBusy 30%).
// 256 WGs = 4 super-domains (8 batches) x 64 jg (12 hidden cols). Per step:
// issue gi loads -> poll merged flags (1 per sd,jg) -> stage all 8 batches'
// h into LDS -> BAR_A -> two back-to-back compute blocks (batches 0-3, 4-7;
// identical shuffle ladders, registers reused) -> h stores -> BAR_B (vmcnt
// drain) -> single flag publish t+1. Rounds/step: 2 -> 1; barriers stay 2.
// W in registers (18 float4/thread), packed fp32 FMA, unchanged.
__global__ __launch_bounds__(RT, 1) void gru_rec(
    const float* __restrict__ gi, const float* __restrict__ w_hh,
    const float* __restrict__ b_hh, float* __restrict__ hb,
    unsigned* __restrict__ flags, float* __restrict__ seq,
    int t0, int Tc)
{
  __shared__ float hs[8][776];    // batch 8sd+c in row c
  const int wg = blockIdx.x;
  const int jg = wg & 63;
  const int sd = wg >> 6;
  const int j0 = jg * 12;
  const int tid = threadIdx.x;
  const int p  = tid >> 6;        // wave 0..5
  const int ks = tid & 63;        // lane

  unsigned* flag_my = flags + ((size_t)(sd * 64) + jg) * 16;

  // ---- W slice into registers: [g][j2][kk], row g*768+j0+2p+j2, 16B at (kk*64+ks)*4
  float4 wreg[3][2][3];
#pragma unroll
  for (int g = 0; g < 3; g++)
#pragma unroll
    for (int j2 = 0; j2 < 2; j2++)
#pragma unroll
      for (int kk = 0; kk < 3; kk++)
        wreg[g][j2][kk] = *(const float4*)(
            w_hh + (size_t)(g * 768 + j0 + 2 * p + j2) * 768 + (kk * 64 + ks) * 4);

  const int j2l = (ks >> 2) & 1;
  const int cl  = ks & 3;
  const int j_out = j0 + 2 * p + j2l;
  const int bA = 8 * sd + cl;         // compute block A: batches 8sd..+3
  const int bB = 8 * sd + 4 + cl;     // compute block B: batches 8sd+4..+7
  const float bhr = b_hh[j_out];
  const float bhz = b_hh[768 + j_out];
  const float bhn = b_hh[1536 + j_out];

  // staging: tid<256; 32 threads per batch, 24 contiguous floats (12 u64) each
  const int sbi = tid >> 5;           // 0..7
  const int sk  = tid & 31;           // 0..31; cols [24sk, 24sk+24) = jg 2sk,2sk+1
  const unsigned* f0 = flags + ((size_t)(sd * 64) + 2 * sk) * 16;
  const unsigned* f1 = flags + ((size_t)(sd * 64) + 2 * sk + 1) * 16;

  const bool hi4 = (ks & 4) != 0;
  const bool hi2 = (ks & 2) != 0;
  const bool hi1 = (ks & 1) != 0;

  for (int tt = 0; tt < Tc; tt++) {
    const int t = t0 + tt;

    // gi loads for both blocks — issued early, latency hides under poll+stage
    float gAr = 0.f, gAz = 0.f, gAn = 0.f;
    float gBr = 0.f, gBz = 0.f, gBn = 0.f;
    if (ks < 8) {
      const float* gA = gi + ((size_t)bA * Tc + tt) * 2304 + j_out;
      gAr = gA[0]; gAz = gA[768]; gAn = gA[1536];
      const float* gB = gi + ((size_t)bB * Tc + tt) * 2304 + j_out;
      gBr = gB[0]; gBz = gB[768]; gBn = gB[1536];
    }

    if (tid < 256) {
      pollge(f0, (unsigned)t);
      pollge(f1, (unsigned)t);
      const unsigned long long* src = (const unsigned long long*)
          (hb + (size_t)(t & 1) * 24576 + (size_t)(8 * sd + sbi) * 768) + sk * 12;
      unsigned long long v[12];
#pragma unroll
      for (int i = 0; i < 12; i++)
        v[i] = __hip_atomic_load(src + i, __ATOMIC_RELAXED, __HIP_MEMORY_SCOPE_AGENT);
      float* dst = &hs[sbi][sk * 24];
#pragma unroll
      for (int q = 0; q < 6; q++) {
        *(float4*)(dst + q * 4) = make_float4(
            __uint_as_float((unsigned)v[2 * q]),
            __uint_as_float((unsigned)(v[2 * q] >> 32)),
            __uint_as_float((unsigned)v[2 * q + 1]),
            __uint_as_float((unsigned)(v[2 * q + 1] >> 32)));
      }
    }
    __syncthreads();   // BAR_A: hs (all 8 batches) ready

    // ---------------- compute block A: batches 8sd..+3 ----------------
    float rA[3];
    {
      vf2 a2[3][2][4];
#pragma unroll
      for (int g = 0; g < 3; g++)
#pragma unroll
        for (int j2 = 0; j2 < 2; j2++)
#pragma unroll
          for (int c = 0; c < 4; c++) a2[g][j2][c] = (vf2)(0.f);
#pragma unroll
      for (int kk = 0; kk < 3; kk++) {
        const int off = (kk * 64 + ks) * 4;
        vf2 hlo[4], hhi[4];
#pragma unroll
        for (int c = 0; c < 4; c++) {
          float4 h = *(const float4*)(&hs[c][0] + off);
          hlo[c] = (vf2){h.x, h.y};
          hhi[c] = (vf2){h.z, h.w};
        }
#pragma unroll
        for (int g = 0; g < 3; g++)
#pragma unroll
          for (int j2 = 0; j2 < 2; j2++) {
            float4 w = wreg[g][j2][kk];
            vf2 wlo = (vf2){w.x, w.y};
            vf2 whi = (vf2){w.z, w.w};
#pragma unroll
            for (int c = 0; c < 4; c++) {
              a2[g][j2][c] = __builtin_elementwise_fma(wlo, hlo[c], a2[g][j2][c]);
              a2[g][j2][c] = __builtin_elementwise_fma(whi, hhi[c], a2[g][j2][c]);
            }
          }
      }
      float acc[3][2][4];
#pragma unroll
      for (int g = 0; g < 3; g++)
#pragma unroll
        for (int j2 = 0; j2 < 2; j2++)
#pragma unroll
          for (int c = 0; c < 4; c++) acc[g][j2][c] = a2[g][j2][c].x + a2[g][j2][c].y;

      float r12[3][4];
#pragma unroll
      for (int g = 0; g < 3; g++)
#pragma unroll
        for (int c = 0; c < 4; c++) {
          float send = hi4 ? acc[g][0][c] : acc[g][1][c];
          float keep = hi4 ? acc[g][1][c] : acc[g][0][c];
          r12[g][c] = keep + __shfl_xor(send, 4);
        }
      float r6[3][2];
#pragma unroll
      for (int g = 0; g < 3; g++)
#pragma unroll
        for (int c2 = 0; c2 < 2; c2++) {
          float send = hi2 ? r12[g][c2] : r12[g][2 + c2];
          float keep = hi2 ? r12[g][2 + c2] : r12[g][c2];
          r6[g][c2] = keep + __shfl_xor(send, 2);
        }
#pragma unroll
      for (int g = 0; g < 3; g++) {
        float send = hi1 ? r6[g][0] : r6[g][1];
        float keep = hi1 ? r6[g][1] : r6[g][0];
        rA[g] = keep + __shfl_xor(send, 1);
      }
#pragma unroll
      for (int g = 0; g < 3; g++) {
        rA[g] += __shfl_xor(rA[g], 8);
        rA[g] += __shfl_xor(rA[g], 16);
        rA[g] += __shfl_xor(rA[g], 32);
      }
    }

    // ---------------- compute block B: batches 8sd+4..+7 ----------------
    float rB[3];
    {
      vf2 a2[3][2][4];
#pragma unroll
      for (int g = 0; g < 3; g++)
#pragma unroll
        for (int j2 = 0; j2 < 2; j2++)
#pragma unroll
          for (int c = 0; c < 4; c++) a2[g][j2][c] = (vf2)(0.f);
#pragma unroll
      for (int kk = 0; kk < 3; kk++) {
        const int off = (kk * 64 + ks) * 4;
        vf2 hlo[4], hhi[4];
#pragma unroll
        for (int c = 0; c < 4; c++) {
          float4 h = *(const float4*)(&hs[4 + c][0] + off);
          hlo[c] = (vf2){h.x, h.y};
          hhi[c] = (vf2){h.z, h.w};
        }
#pragma unroll
        for (int g = 0; g < 3; g++)
#pragma unroll
          for (int j2 = 0; j2 < 2; j2++) {
            float4 w = wreg[g][j2][kk];
            vf2 wlo = (vf2){w.x, w.y};
            vf2 whi = (vf2){w.z, w.w};
#pragma unroll
            for (int c = 0; c < 4; c++) {
              a2[g][j2][c] = __builtin_elementwise_fma(wlo, hlo[c], a2[g][j2][c]);
              a2[g][j2][c] = __builtin_elementwise_fma(whi, hhi[c], a2[g][j2][c]);
            }
          }
      }
      float acc[3][2][4];
#pragma unroll
      for (int g = 0; g < 3; g++)
#pragma unroll
        for (int j2 = 0; j2 < 2; j2++)
#pragma unroll
          for (int c = 0; c < 4; c++) acc[g][j2][c] = a2[g][j2][c].x + a2[g][j2][c].y;

      float r12[3][4];
#pragma unroll
      for (int g = 0; g < 3; g++)
#pragma unroll
        for (int c = 0; c < 4; c++) {
          float send = hi4 ? acc[g][0][c] : acc[g][1][c];
          float keep = hi4 ? acc[g][1][c] : acc[g][0][c];
          r12[g][c] = keep + __shfl_xor(send, 4);
        }
      float r6[3][2];
#pragma unroll
      for (int g = 0; g < 3; g++)
#pragma unroll
        for (int c2 = 0; c2 < 2; c2++) {
          float send = hi2 ? r12[g][c2] : r12[g][2 + c2];
          float keep = hi2 ? r12[g][2 + c2] : r12[g][c2];
          r6[g][c2] = keep + __shfl_xor(send, 2);
        }
#pragma unroll
      for (int g = 0; g < 3; g++) {
        float send = hi1 ? r6[g][0] : r6[g][1];
        float keep = hi1 ? r6[g][1] : r6[g][0];
        rB[g] = keep + __shfl_xor(send, 1);
      }
#pragma unroll
      for (int g = 0; g < 3; g++) {
        rB[g] += __shfl_xor(rB[g], 8);
        rB[g] += __shfl_xor(rB[g], 16);
        rB[g] += __shfl_xor(rB[g], 32);
      }
    }

    if (ks < 8) {
      {
        float hp = hs[cl][j_out];
        float r = 1.f / (1.f + __expf(-(gAr + rA[0] + bhr)));
        float z = 1.f / (1.f + __expf(-(gAz + rA[1] + bhz)));
        float n = tanhf(gAn + r * (rA[2] + bhn));
        float hv = (1.f - z) * n + z * hp;
        __hip_atomic_store(hb + (size_t)((t + 1) & 1) * 24576 + (size_t)bA * 768 + j_out,
                           hv, __ATOMIC_RELAXED, __HIP_MEMORY_SCOPE_AGENT);
        seq[((size_t)bA * 1024 + t) * 768 + j_out] = hv;
      }
      {
        float hp = hs[4 + cl][j_out];
        float r = 1.f / (1.f + __expf(-(gBr + rB[0] + bhr)));
        float z = 1.f / (1.f + __expf(-(gBz + rB[1] + bhz)));
        float n = tanhf(gBn + r * (rB[2] + bhn));
        float hv = (1.f - z) * n + z * hp;
        __hip_atomic_store(hb + (size_t)((t + 1) & 1) * 24576 + (size_t)bB * 768 + j_out,
                           hv, __ATOMIC_RELAXED, __HIP_MEMORY_SCOPE_AGENT);
        seq[((size_t)bB * 1024 + t) * 768 + j_out] = hv;
      }
    }
    __syncthreads();   // BAR_B: drains all h stores (per-wave vmcnt(0))
    if (tid == 0)
      __hip_atomic_store(flag_my, (unsigned)(t + 1), __ATOMIC_RELAXED, __HIP_MEMORY_SCOPE_AGENT);
  }
}

extern "C" void kernel_launch(void* const* d_in, const int* in_sizes, int n_in,
                              void* d_out, int out_size, void* d_ws, size_t ws_size,
                              hipStream_t stream) {
  const float* feat  = (const float*)d_in[0];
  const float* w_ih0 = (const float*)d_in[2];
  const float* w_hh0 = (const float*)d_in[3];
  const float* b_ih0 = (const float*)d_in[4];
  const float* b_hh0 = (const float*)d_in[5];
  const float* w_ih1 = (const float*)d_in[6];
  const float* w_hh1 = (const float*)d_in[7];
  const float* b_ih1 = (const float*)d_in[8];
  const float* b_hh1 = (const float*)d_in[9];
  const float* fc_w  = (const float*)d_in[10];
  const float* fc_b  = (const float*)d_in[11];
  const float* out_w = (const float*)d_in[12];
  const float* out_b = (const float*)d_in[13];
  float* out = (float*)d_out;

  const int Tc = 256;
  const int McChunk = 32 * Tc;

  float* proj = (float*)d_ws;                               // 18,874,368 f
  float* seq  = proj + (size_t)32 * Tc * 2304;              // 25,165,824 f
  float* hbuf = seq + (size_t)25165824;                     // 2*24576 f
  unsigned* flags = (unsigned*)(hbuf + 2 * 24576);          // 256 x 64B = 16 KB used

  // ---- layer 0 ----
  hipMemsetAsync(hbuf, 0, 2 * 24576 * sizeof(float), stream);
  hipMemsetAsync(flags, 0, 32768, stream);
  for (int c = 0; c < 4; c++) {
    gemm_bt_f32<<<dim3(36, McChunk / 128), dim3(256), 0, stream>>>(
        feat, w_ih0, b_ih0, proj, McChunk, 2304, 768, 8, 1024, c * Tc, 0);
    gru_rec<<<dim3(RNWG), dim3(RT), 0, stream>>>(
        proj, w_hh0, b_hh0, hbuf, flags, seq, c * Tc, Tc);
  }
  // ---- layer 1 ----
  hipMemsetAsync(hbuf, 0, 2 * 24576 * sizeof(float), stream);
  hipMemsetAsync(flags, 0, 32768, stream);
  for (int c = 0; c < 4; c++) {
    gemm_bt_f32<<<dim3(36, McChunk / 128), dim3(256), 0, stream>>>(
        seq, w_ih1, b_ih1, proj, McChunk, 2304, 768, 8, 1024, c * Tc, 0);
    gru_rec<<<dim3(RNWG), dim3(RT), 0, stream>>>(
        proj, w_hh1, b_hh1, hbuf, flags, seq, c * Tc, Tc);
  }
  // ---- fc + SELU ----
  gemm_bt_f32<<<dim3(8, 256), dim3(256), 0, stream>>>(
      seq, fc_w, fc_b, proj, 32768, 512, 768, 15, 32768, 0, 1);
  // ---- out + tanh ----
  gemm_bt_f32<<<dim3(1, 256), dim3(256), 0, stream>>>(
      proj, out_w, out_b, out, 32768, 39, 512, 15, 32768, 0, 2);
}